// Round 6
// baseline (16919.545 us; speedup 1.0000x reference)
//
#include <hip/hip_runtime.h>
#include <math.h>

#define BB 32
#define NN 577
#define DD 384
#define HD 1536
#define LL 12
#define MP 640   // padded mem/key length; multiple of 64
#define NRPT 4
#define QR (BB*NN)      // 18464 q rows
#define QP 18560        // q rows padded to 145 tiles of 128
#define KR (BB*MP)      // 20480 k rows

typedef __attribute__((ext_vector_type(8))) short bf16x8;
typedef __attribute__((ext_vector_type(4))) float f32x4;

__device__ __forceinline__ unsigned short f2bf(float f){
  unsigned u = __builtin_bit_cast(unsigned, f);
  u += 0x7fffu + ((u >> 16) & 1u);
  return (unsigned short)(u >> 16);
}
__device__ __forceinline__ float bf2f(unsigned short s){
  unsigned u = ((unsigned)s) << 16;
  return __builtin_bit_cast(float, u);
}

__device__ __forceinline__ void async16(void* lds, const void* g){
  __builtin_amdgcn_global_load_lds(
      (const __attribute__((address_space(1))) unsigned int*)g,
      (__attribute__((address_space(3))) unsigned int*)lds, 16, 0, 0);
}

// ---------------- fused repeat-prep ----------------
__global__ void prep_k(float* __restrict__ x, const float* __restrict__ xp,
                       float* __restrict__ cls_r, const float* __restrict__ cls_hist,
                       unsigned short* __restrict__ mem, int r){
  int i = blockIdx.x * 256 + threadIdx.x;
  if (i >= BB*MP*DD) return;
  int d = i % DD;
  int n = (i / DD) % MP;
  int b = i / (MP*DD);
  float v;
  if (n == 0){ v = x[(size_t)b*NN*DD + d]; cls_r[b*DD + d] = v; }
  else if (n < NN){ v = xp[((size_t)b*NN + n)*DD + d]; x[((size_t)b*NN + n)*DD + d] = v; }
  else if (n < NN + r){ v = cls_hist[(size_t)(n-NN)*BB*DD + b*DD + d]; }
  else v = 0.f;
  mem[i] = f2bf(v);
}

// per-layer weight cast
__global__ void castL_k(const float* __restrict__ qkvw, const float* __restrict__ pw,
                        const float* __restrict__ f1w, const float* __restrict__ f2w,
                        unsigned short* __restrict__ wbuf){
  int i = blockIdx.x * 256 + threadIdx.x;
  const int QKV = 3*DD*DD;
  const int PRJ = DD*DD;
  const int F1  = HD*DD;
  const int TOT = QKV + PRJ + 2*F1;
  if (i >= TOT) return;
  float v;
  if (i < QKV) v = qkvw[i];
  else if (i < QKV+PRJ) v = pw[i-QKV];
  else if (i < QKV+PRJ+F1) v = f1w[i-QKV-PRJ];
  else v = f2w[i-QKV-PRJ-F1];
  wbuf[i] = f2bf(v);
}

// ---------------- LayerNorm: 4 rows per block (fp32 in) ----------------
__global__ __launch_bounds__(256) void ln4_k(const float* __restrict__ in, const float* __restrict__ w,
                                             const float* __restrict__ bias, unsigned short* __restrict__ out,
                                             int nrows){
  int row = blockIdx.x*4 + (threadIdx.x >> 6);
  if (row >= nrows) return;
  int lane = threadIdx.x & 63;
  const float* p = in + (size_t)row*DD;
  float v[6];
  float s = 0.f;
  #pragma unroll
  for (int i=0;i<6;i++){ float t = p[lane + i*64]; v[i] = t; s += t; }
  #pragma unroll
  for (int o=32;o;o>>=1) s += __shfl_xor(s, o, 64);
  float mu = s * (1.f/DD);
  float q = 0.f;
  #pragma unroll
  for (int i=0;i<6;i++){ float t = v[i]-mu; q += t*t; }
  #pragma unroll
  for (int o=32;o;o>>=1) q += __shfl_xor(q, o, 64);
  float rs = rsqrtf(q*(1.f/DD) + 1e-6f);
  unsigned short* po = out + (size_t)row*DD;
  #pragma unroll
  for (int i=0;i<6;i++){
    int c = lane + i*64;
    po[c] = f2bf((v[i]-mu)*rs*w[c] + bias[c]);
  }
}

// merged LN for q (scaled by 1/sqrt(D)) and k; bf16x2 vectorized
__global__ __launch_bounds__(256) void lnqk_k(const unsigned short* __restrict__ qraw,
                                              const unsigned short* __restrict__ kraw,
                                              const float* __restrict__ qw, const float* __restrict__ qbias,
                                              const float* __restrict__ kw, const float* __restrict__ kbias,
                                              unsigned short* __restrict__ qo, unsigned short* __restrict__ ko){
  int row = blockIdx.x*4 + (threadIdx.x >> 6);
  int lane = threadIdx.x & 63;
  bool isq = row < QR;   // QR % 4 == 0: no intra-block divergence
  const unsigned int* p = (const unsigned int*)(isq ? qraw + (size_t)row*DD : kraw + (size_t)(row-QR)*DD);
  const float* w  = isq ? qw : kw;
  const float* bs = isq ? qbias : kbias;
  unsigned int* po = (unsigned int*)(isq ? qo + (size_t)row*DD : ko + (size_t)(row-QR)*DD);
  float scale = isq ? 0.05103103588f : 1.0f;
  float v[6];
  float s = 0.f;
  #pragma unroll
  for (int i=0;i<3;i++){
    unsigned u = p[lane + i*64];
    float a = bf2f((unsigned short)u), b = bf2f((unsigned short)(u>>16));
    v[2*i] = a; v[2*i+1] = b; s += a + b;
  }
  #pragma unroll
  for (int o=32;o;o>>=1) s += __shfl_xor(s, o, 64);
  float mu = s * (1.f/DD);
  float q = 0.f;
  #pragma unroll
  for (int i=0;i<6;i++){ float t = v[i]-mu; q += t*t; }
  #pragma unroll
  for (int o=32;o;o>>=1) q += __shfl_xor(q, o, 64);
  float rs = rsqrtf(q*(1.f/DD) + 1e-6f);
  #pragma unroll
  for (int i=0;i<3;i++){
    int c0 = 2*(lane + i*64);
    unsigned short lo = f2bf(((v[2*i]  -mu)*rs*w[c0]   + bs[c0]  ) * scale);
    unsigned short hi = f2bf(((v[2*i+1]-mu)*rs*w[c0+1] + bs[c0+1]) * scale);
    po[lane + i*64] = (unsigned)lo | ((unsigned)hi << 16);
  }
}

// ---------------- 128x128 LDS-staged GEMM, BK=64 ----------------
// C[row, col] = sum_k A[row][k] * B[col][k] (+bias). Optional row-split:
// tiles with row0 >= rowSplit use W2/bias2 and store-limit orows2 (qk merge).
template<int EPI>
__global__ __launch_bounds__(256) void gemm128(
    const unsigned short* __restrict__ A, int lda, int arows, long sA,
    const unsigned short* __restrict__ B, int ldb, int brows, long sB,
    const float* __restrict__ bias,
    int K, int N,
    float* __restrict__ outF, unsigned short* __restrict__ outB,
    int ldo, int orows, long sO,
    const float* __restrict__ ls,
    int rowSplit, const unsigned short* __restrict__ B2,
    const float* __restrict__ bias2, int orows2){

  __shared__ unsigned short a_sh[2][128*32];
  __shared__ unsigned short b_sh[2][128*32];

  int tid  = threadIdx.x;
  int wave = tid >> 6, lane = tid & 63;
  int lr = lane & 15, kg = lane >> 4;
  int wm = wave >> 1, wn = wave & 1;
  int z = blockIdx.z;
  int row0 = blockIdx.y * 128;
  int col0 = blockIdx.x * 128;

  bool second = row0 >= rowSplit;
  const unsigned short* Bu = second ? B2 : B;
  const float* biasu = second ? bias2 : bias;
  int limit = second ? orows2 : orows;

  const unsigned short* Ab = A + (size_t)z*sA;
  const unsigned short* Bb = Bu + (size_t)z*sB;

  f32x4 zf = {0.f,0.f,0.f,0.f};
  f32x4 acc[4][4];
  #pragma unroll
  for (int i=0;i<4;i++)
    #pragma unroll
    for (int j=0;j<4;j++) acc[i][j] = zf;

  int ra[2], rb[2], kc[2];
  #pragma unroll
  for (int it=0; it<2; it++){
    int c = tid + it*256;
    int r = row0 + (c>>2); if (r > arows-1) r = arows-1;
    ra[it] = r;
    r = col0 + (c>>2); if (r > brows-1) r = brows-1;
    rb[it] = r;
    kc[it] = (c&3)*8;
  }

  for (int k0 = 0; k0 < K; k0 += 64){
    #pragma unroll
    for (int p=0;p<2;p++){
      #pragma unroll
      for (int it=0; it<2; it++){
        unsigned short* la = &a_sh[p][(it*256 + wave*64)*8];
        unsigned short* lb = &b_sh[p][(it*256 + wave*64)*8];
        async16(la, Ab + (size_t)ra[it]*lda + k0 + p*32 + kc[it]);
        async16(lb, Bb + (size_t)rb[it]*ldb + k0 + p*32 + kc[it]);
      }
    }
    __syncthreads();
    #pragma unroll
    for (int p=0;p<2;p++){
      bf16x8 af[4], bfr[4];
      #pragma unroll
      for (int i=0;i<4;i++){
        af[i]  = *(const bf16x8*)&a_sh[p][(wm*64 + i*16 + lr)*32 + kg*8];
        bfr[i] = *(const bf16x8*)&b_sh[p][(wn*64 + i*16 + lr)*32 + kg*8];
      }
      #pragma unroll
      for (int i=0;i<4;i++)
        #pragma unroll
        for (int j=0;j<4;j++)
          acc[i][j] = __builtin_amdgcn_mfma_f32_16x16x32_bf16(af[i], bfr[j], acc[i][j], 0,0,0);
    }
    __syncthreads();
  }

  float* oF = outF ? outF + (size_t)z*sO : nullptr;
  unsigned short* oB = outB ? outB + (size_t)z*sO : nullptr;

  #pragma unroll
  for (int mi=0;mi<4;mi++)
    #pragma unroll
    for (int ni=0;ni<4;ni++)
      #pragma unroll
      for (int r=0;r<4;r++){
        int row = row0 + wm*64 + mi*16 + kg*4 + r;
        int col = col0 + wn*64 + ni*16 + lr;
        if (row >= limit || col >= N) continue;
        float vv = acc[mi][ni][r];
        size_t idx = (size_t)row*ldo + col;
        if (EPI == 0){
          if (biasu) vv += biasu[col];
          oB[idx] = f2bf(vv);
        } else if (EPI == 1){
          vv += biasu[row];
          oB[idx] = f2bf(vv);
        } else if (EPI == 2){
          vv += biasu[col];
          oF[idx] = vv*ls[col] + oF[idx];
        } else {
          vv += biasu[col];
          float g = 0.5f*vv*(1.f + erff(vv*0.70710678118f));
          oB[idx] = f2bf(g);
        }
      }
}

// ---------------- fused flash attention + an-LayerNorm ----------------
__global__ __launch_bounds__(256, 2) void attn_k(
    const unsigned short* __restrict__ qs,
    const unsigned short* __restrict__ kb,
    const unsigned short* __restrict__ vT,
    const float* __restrict__ anw, const float* __restrict__ anb,
    unsigned short* __restrict__ out, int M){

  __shared__ unsigned short k_sh[32*384];   // swizzled
  __shared__ unsigned short v_sh[384*32];   // swizzled
  __shared__ unsigned short p_sh[64*40];    // P in A-layout, stride 40 (2-way banks)

  int tid = threadIdx.x;
  int wv = tid >> 6, lane = tid & 63;
  int lr = lane & 15, kg = lane >> 4;
  int b = blockIdx.y, qt0 = blockIdx.x * 64;

  bf16x8 qf[12];
  {
    int qrow = qt0 + wv*16 + lr; if (qrow > NN-1) qrow = NN-1;
    const unsigned short* qp = qs + ((size_t)b*NN + qrow)*DD;
    #pragma unroll
    for (int ks=0; ks<12; ks++) qf[ks] = *(const bf16x8*)(qp + ks*32 + kg*8);
  }

  f32x4 zf = {0.f,0.f,0.f,0.f};
  f32x4 O[24];
  #pragma unroll
  for (int i=0;i<24;i++) O[i] = zf;
  float m_run[4], l_run[4];
  #pragma unroll
  for (int r=0;r<4;r++){ m_run[r] = -INFINITY; l_run[r] = 0.f; }

  for (int kt=0; kt<19; kt++){
    __syncthreads();   // prev PV done reading k_sh/v_sh
    #pragma unroll
    for (int i=0;i<6;i++){
      int L = i*256 + tid;
      int row = L/48, c = L%48;
      int gc = (c & ~7) | ((c ^ row) & 7);
      async16(&k_sh[L*8], kb + ((size_t)b*MP + kt*32 + row)*DD + gc*8);
    }
    #pragma unroll
    for (int i=0;i<6;i++){
      int L = i*256 + tid;
      int row = L>>2;
      int gc = (L&3) ^ (row&3);
      async16(&v_sh[L*8], vT + ((size_t)b*DD + row)*MP + kt*32 + gc*8);
    }
    __syncthreads();   // staged data visible

    f32x4 s[2] = {zf, zf};
    #pragma unroll
    for (int ks=0; ks<12; ks++){
      int c = ks*4 + kg;
      #pragma unroll
      for (int nk=0; nk<2; nk++){
        int krow = nk*16 + lr;
        bf16x8 bk = *(const bf16x8*)&k_sh[krow*DD + ((c & ~7) | ((c ^ krow)&7))*8];
        s[nk] = __builtin_amdgcn_mfma_f32_16x16x32_bf16(qf[ks], bk, s[nk], 0,0,0);
      }
    }
    #pragma unroll
    for (int nk=0; nk<2; nk++){
      if (kt*32 + nk*16 + lr >= M){
        s[nk][0] = -INFINITY; s[nk][1] = -INFINITY; s[nk][2] = -INFINITY; s[nk][3] = -INFINITY;
      }
    }
    float al[4];
    #pragma unroll
    for (int r=0;r<4;r++){
      float v = fmaxf(s[0][r], s[1][r]);
      v = fmaxf(v, __shfl_xor(v, 1, 64));
      v = fmaxf(v, __shfl_xor(v, 2, 64));
      v = fmaxf(v, __shfl_xor(v, 4, 64));
      v = fmaxf(v, __shfl_xor(v, 8, 64));
      float mn = fmaxf(m_run[r], v);
      al[r] = __expf(m_run[r] - mn);
      m_run[r] = mn;
    }
    #pragma unroll
    for (int nk=0;nk<2;nk++)
      #pragma unroll
      for (int r=0;r<4;r++)
        s[nk][r] = __expf(s[nk][r] - m_run[r]);
    #pragma unroll
    for (int r=0;r<4;r++){
      float v = s[0][r] + s[1][r];
      v += __shfl_xor(v, 1, 64);
      v += __shfl_xor(v, 2, 64);
      v += __shfl_xor(v, 4, 64);
      v += __shfl_xor(v, 8, 64);
      l_run[r] = al[r]*l_run[r] + v;
    }
    // p_sh is wave-local (write rows wv*16+kg*4+r, read rows wv*16+lr):
    // in-order LDS within a wave -> no barrier needed before PV.
    #pragma unroll
    for (int nk=0;nk<2;nk++)
      #pragma unroll
      for (int r=0;r<4;r++)
        p_sh[(wv*16 + kg*4 + r)*40 + nk*16 + lr] = f2bf(s[nk][r]);
    #pragma unroll
    for (int ni=0;ni<24;ni++)
      #pragma unroll
      for (int r=0;r<4;r++) O[ni][r] *= al[r];

    bf16x8 ap = *(const bf16x8*)&p_sh[(wv*16 + lr)*40 + kg*8];
    #pragma unroll
    for (int ni=0;ni<24;ni++){
      int d = ni*16 + lr;
      bf16x8 bv = *(const bf16x8*)&v_sh[d*32 + ((kg ^ (d&3))*8)];
      O[ni] = __builtin_amdgcn_mfma_f32_16x16x32_bf16(ap, bv, O[ni], 0,0,0);
    }
  }

  // epilogue: normalize by l, then LN(an) — wave-local
  float inv[4];
  #pragma unroll
  for (int r=0;r<4;r++) inv[r] = 1.f / l_run[r];
  float s1[4] = {0,0,0,0}, s2[4] = {0,0,0,0};
  #pragma unroll
  for (int ni=0;ni<24;ni++)
    #pragma unroll
    for (int r=0;r<4;r++){
      float x = O[ni][r]*inv[r];
      O[ni][r] = x;
      s1[r] += x; s2[r] += x*x;
    }
  #pragma unroll
  for (int r=0;r<4;r++){
    #pragma unroll
    for (int o=1;o<16;o<<=1){ s1[r] += __shfl_xor(s1[r], o, 64); s2[r] += __shfl_xor(s2[r], o, 64); }
  }
  float mu[4], rs[4];
  #pragma unroll
  for (int r=0;r<4;r++){
    mu[r] = s1[r]*(1.f/DD);
    float var = s2[r]*(1.f/DD) - mu[r]*mu[r];
    rs[r] = rsqrtf(fmaxf(var, 0.f) + 1e-6f);
  }
  int rowb = qt0 + wv*16 + kg*4;
  #pragma unroll
  for (int ni=0;ni<24;ni++){
    int col = ni*16 + lr;
    float wc = anw[col], bc = anb[col];
    #pragma unroll
    for (int r=0;r<4;r++){
      int qrow = rowb + r;
      if (qrow < NN)
        out[((size_t)b*NN + qrow)*DD + col] = f2bf((O[ni][r]-mu[r])*rs[r]*wc + bc);
    }
  }
}

// ---------------- launcher ----------------

extern "C" void kernel_launch(void* const* d_in, const int* in_sizes, int n_in,
                              void* d_out, int out_size, void* d_ws, size_t ws_size,
                              hipStream_t stream){
  const float* x_in = (const float*)d_in[0];
  const float* n1w  = (const float*)d_in[1];
  const float* n1b  = (const float*)d_in[2];
  const float* qkvw = (const float*)d_in[3];
  const float* qkvb = (const float*)d_in[4];
  const float* qnw  = (const float*)d_in[5];
  const float* qnb  = (const float*)d_in[6];
  const float* knw  = (const float*)d_in[7];
  const float* knb  = (const float*)d_in[8];
  const float* anw  = (const float*)d_in[9];
  const float* anb  = (const float*)d_in[10];
  const float* pw   = (const float*)d_in[11];
  const float* pb   = (const float*)d_in[12];
  const float* ls1  = (const float*)d_in[13];
  const float* n2w  = (const float*)d_in[14];
  const float* n2b  = (const float*)d_in[15];
  const float* f1w  = (const float*)d_in[16];
  const float* f1b  = (const float*)d_in[17];
  const float* f2w  = (const float*)d_in[18];
  const float* f2bb = (const float*)d_in[19];
  const float* ls2  = (const float*)d_in[20];

  char* ws = (char*)d_ws;
  size_t off = 0;
  auto alloc = [&](size_t bytes)->char* {
    char* p = ws + off;
    off = (off + bytes + 255) & ~(size_t)255;
    return p;
  };

  const int QKV = 3*DD*DD, PRJ = DD*DD, F1 = HD*DD;
  const size_t WTOT = (size_t)QKV + PRJ + 2*F1;
  const size_t SLOT = (size_t)BB*MP*DD;          // 7,864,320 elems
  const size_t XNSZ = (size_t)QP*DD;             // 7,127,040 elems

  unsigned short* wbuf  = (unsigned short*)alloc(WTOT*2);
  float*          cls_h = (float*)         alloc((size_t)NRPT*BB*DD*4);
  // A-region: [xn (QP rows) | mem (KR rows)] contiguous for merged qk GEMM
  unsigned short* xnbuf = (unsigned short*)alloc((XNSZ + SLOT + 5*SLOT)*2);
  unsigned short* mem_bf= xnbuf + XNSZ;
  unsigned short* S1 = mem_bf + SLOT;
  unsigned short* S2 = S1 + SLOT;
  unsigned short* S3 = S2 + SLOT;
  unsigned short* S4 = S3 + SLOT;
  unsigned short* S5 = S4 + SLOT;

  // optional full weight cache (all 12 layers) if workspace allows
  unsigned short* wbufAll = nullptr;
  if (ws_size >= off + 12*WTOT*2 + 256)
    wbufAll = (unsigned short*)alloc(12*WTOT*2);

  // S0 aliases xn slab (xn: steps 1-2; prodn: 5-6; x2: 7-8 — disjoint; cap 7.127M >= 7.09M)
  unsigned short* S0 = xnbuf;
  unsigned short* xn    = xnbuf;  // ln1 out, rows 0..QR-1 (pad rows stale, clamped/guarded)
  unsigned short* qkraw = S1;     // merged q|k gemm out: q rows [0,QP), k rows [QP,QP+KR) (spans S1S2)
  unsigned short* qraw  = qkraw;
  unsigned short* kraw  = qkraw + (size_t)QP*DD;
  unsigned short* qb    = S3;     // lnqk q out
  unsigned short* kb    = S4;     // lnqk k out
  unsigned short* vT    = S5;     // vT gemm out
  unsigned short* prodn = S0;     // attn out
  unsigned short* x2    = S0;     // ln2 out
  unsigned short* h     = S1;     // fc1 out (spans S1..S4)

  float* xf = (float*)d_out;

  auto cg = [](size_t n){ return dim3((unsigned)((n + 255) / 256)); };

  hipMemcpyAsync(xf, x_in, (size_t)BB*NN*DD*4, hipMemcpyDeviceToDevice, stream);

  if (wbufAll)
    for (int l = 0; l < LL; l++)
      castL_k<<<cg(WTOT),256,0,stream>>>(qkvw + (size_t)l*QKV, pw + (size_t)l*PRJ,
                                         f1w + (size_t)l*F1, f2w + (size_t)l*F1,
                                         wbufAll + (size_t)l*WTOT);

  const int RT  = QP/128;              // 145
  const int RTK = KR/128;              // 160
  const int MAXI = 0x7fffffff;

  for (int r = 0; r < NRPT; r++){
    int M = NN + r;
    prep_k<<<cg((size_t)BB*MP*DD),256,0,stream>>>(xf, x_in, cls_h + (size_t)r*BB*DD, cls_h, mem_bf, r);
    for (int l = 0; l < LL; l++){
      unsigned short* wl;
      if (wbufAll) wl = wbufAll + (size_t)l*WTOT;
      else {
        castL_k<<<cg(WTOT),256,0,stream>>>(qkvw + (size_t)l*QKV, pw + (size_t)l*PRJ,
                                           f1w + (size_t)l*F1, f2w + (size_t)l*F1, wbuf);
        wl = wbuf;
      }
      unsigned short* wq = wl;
      unsigned short* wp = wl + QKV;
      unsigned short* w1 = wl + QKV + PRJ;
      unsigned short* w2 = wl + QKV + PRJ + F1;

      // 1: ln1 -> xn
      ln4_k<<<cg((size_t)QR*64),256,0,stream>>>(xf, n1w + l*DD, n1b + l*DD, xn, QR);
      // 2: merged q|k GEMM over contiguous [xn|mem] rows
      gemm128<0><<<dim3(3,RT+RTK,1),256,0,stream>>>(
          xn,384,QP+KR,0, wq,384,384,0, qkvb + l*3*DD, 384,384,
          nullptr,qkraw,384,QR,0, nullptr,
          QP, wq + (size_t)DD*DD, qkvb + l*3*DD + DD, QP+KR);
      // 3: vT = Wv @ mem^T (+bv by row), batched
      gemm128<1><<<dim3(MP/128,3,BB),256,0,stream>>>(
          wq + (size_t)2*DD*DD,384,384,0, mem_bf,384,MP,(long)MP*DD,
          qkvb + l*3*DD + 2*DD, 384,MP, nullptr,vT,MP,384,(long)DD*MP, nullptr,
          MAXI, nullptr, nullptr, 0);
      // 4: ln q (pre-scaled) + ln k
      lnqk_k<<<(QR+KR)/4,256,0,stream>>>(qraw, kraw, qnw + l*DD, qnb + l*DD,
                                         knw + l*DD, knb + l*DD, qb, kb);
      // 5: flash attention + an-LN
      attn_k<<<dim3(10,BB),256,0,stream>>>(qb, kb, vT, anw + l*DD, anb + l*DD, prodn, M);
      // 6: x += ls1 * (prodn @ Wp^T + bp)
      gemm128<2><<<dim3(3,RT,1),256,0,stream>>>(
          prodn,384,QR,0, wp,384,384,0, pb + l*DD, 384,384,
          xf,nullptr,384,QR,0, ls1 + l*DD, MAXI, nullptr, nullptr, 0);
      // 7: ln2 -> x2
      ln4_k<<<cg((size_t)QR*64),256,0,stream>>>(xf, n2w + l*DD, n2b + l*DD, x2, QR);
      // 8: h = gelu(x2 @ W1^T + b1)
      gemm128<3><<<dim3(HD/128,RT,1),256,0,stream>>>(
          x2,384,QR,0, w1,384,HD,0, f1b + l*HD, 384,HD,
          nullptr,h,HD,QR,0, nullptr, MAXI, nullptr, nullptr, 0);
      // 9: x += ls2 * (h @ W2^T + b2)
      gemm128<2><<<dim3(3,RT,1),256,0,stream>>>(
          h,HD,QR,0, w2,HD,384,0, f2bb + l*DD, HD,384,
          xf,nullptr,384,QR,0, ls2 + l*DD, MAXI, nullptr, nullptr, 0);
    }
  }
}